// Round 12
// baseline (531.770 us; speedup 1.0000x reference)
//
#include <hip/hip_runtime.h>
#include <hip/hip_bf16.h>
#include <math.h>

#define Bsz 1024
#define Nn  11
#define Ff  512
#define Zi  10
#define G3  1536

typedef __attribute__((ext_vector_type(8))) short bfrag;
typedef __attribute__((ext_vector_type(16))) float f32x16;

__device__ __forceinline__ unsigned f2bf(float f) {
    __hip_bfloat16 h = __float2bfloat16(f);
    return (unsigned)*reinterpret_cast<unsigned short*>(&h);
}
__device__ __forceinline__ uint4 pack8(float v0, float v1, float v2, float v3,
                                       float v4, float v5, float v6, float v7) {
    uint4 pk;
    pk.x = f2bf(v0) | (f2bf(v1) << 16);
    pk.y = f2bf(v2) | (f2bf(v3) << 16);
    pk.z = f2bf(v4) | (f2bf(v5) << 16);
    pk.w = f2bf(v6) | (f2bf(v7) << 16);
    return pk;
}
__device__ __forceinline__ void pair_decode(int mode, int p, int& pi, int& pj) {
    if (mode == 0) { int r = p, i = 0; while (r >= Nn - i) { r -= Nn - i; ++i; } pi = i; pj = i + r; }
    else { pi = p; pj = Zi; }
}
// async global->LDS, 16B/lane; dst must be wave-uniform base (+lane*16 by HW)
__device__ __forceinline__ void gl_lds16(const void* src, void* dst) {
    __builtin_amdgcn_global_load_lds((const __attribute__((address_space(1))) void*)src,
                                     (__attribute__((address_space(3))) void*)dst, 16, 0, 0);
}

// ---------------------------------------------------------------------------
__global__ void init_col_kernel(const float* __restrict__ nf, float* __restrict__ col) {
    int idx = blockIdx.x * 256 + threadIdx.x;
    int b = idx >> 9, f = idx & 511;
    col[idx] = nf[(b * Nn + Zi) * Ff + f];
}

// ---------------------------------------------------------------------------
// pack fp32 W[g][k] -> bf16 kq-plane-major chunks (contiguous staged slices)
// ---------------------------------------------------------------------------
__global__ void pack_w_kernel(const float* __restrict__ src,
                              unsigned short* __restrict__ dst, int lgBW) {
    int idx = blockIdx.x * 256 + threadIdx.x;   // total G*64 chunks
    int g = idx >> 6, kq = idx & 63;
    int nb = g >> lgBW, gl = g & ((1 << lgBW) - 1);
    const float* s = src + g * Ff + kq * 8;
    float4 a = *(const float4*)s, b = *(const float4*)(s + 4);
    uint4 pk = pack8(a.x, a.y, a.z, a.w, b.x, b.y, b.z, b.w);
    long long dc = (((long long)(nb << 6) + kq) << lgBW) + gl;
    *(uint4*)((char*)dst + dc * 16) = pk;
}

// ---------------------------------------------------------------------------
// Fused link MLP. Block = 32 rows (1 pair x 32 batches) x 512 cols, 512 thr,
// 8 waves, wave tile 32x64. K_STEP = 16.
// E resident 32 KB (h1 in-place). W: 3-deep pipelined 16KB slices staged via
// gl_lds; per-step counted s_waitcnt vmcnt(2) + raw s_barrier -> the slice
// consumed next was staged 2 steps (~1200cy) ago: L2 latency fully hidden.
// LDS = 80 KB exactly -> 2 blocks/CU.
// ---------------------------------------------------------------------------
__global__ __launch_bounds__(512, 4) void link_kernel(
    const float* __restrict__ nf, const float* __restrict__ colp,
    const unsigned short* __restrict__ W1p, const float* __restrict__ b1,
    const unsigned short* __restrict__ W2p, const float* __restrict__ b2,
    const float* __restrict__ w_out, const float* __restrict__ b_out,
    float* __restrict__ adj, int mode)
{
    __shared__ __align__(16) char Eb[64 * 32 * 16];      // 32,768 B
    __shared__ __align__(16) char Wb[3][2 * 512 * 16];   // 3 x 16,384 B

    const int tid = threadIdx.x;
    const int pr  = blockIdx.x >> 5;
    const int bc  = blockIdx.x & 31;
    int pi, pj; pair_decode(mode, pr, pi, pj);

    const int wid = tid >> 6;
    const int l   = tid & 63;
    const int lr  = l & 31;
    const int kg  = l >> 5;

    // stage a 16KB W K-slice (contiguous in packed layout), async, no regs
    auto stageW = [&](int tgt) {   // tgt = global step index 0..63
        const unsigned short* Wsp = (tgt >= 32) ? W2p : W1p;
        const int kq0 = (tgt & 31) * 2;
        char* dstb = (char*)Wb[tgt % 3];
#pragma unroll
        for (int i = 0; i < 2; ++i) {
            int cb = i * 512 + wid * 64;           // wave-uniform chunk base
            gl_lds16(Wsp + (kq0 * 512 + cb + l) * 8, dstb + cb * 16);
        }
    };

    // ---- prime pipeline: slices 0 and 1 ----
    stageW(0);
    stageW(1);

    // ---- E build: row = tid>>4, 32 k per thread (coalesced 128B reads) ----
    {
        const int row = tid >> 4;
        const int kc  = tid & 15;
        const int b   = bc * 32 + row;
        const float* xi = (pi == Zi) ? (colp + b * Ff) : (nf + (b * Nn + pi) * Ff);
        const float* xj = (pj == Zi) ? (colp + b * Ff) : (nf + (b * Nn + pj) * Ff);
#pragma unroll
        for (int i = 0; i < 4; ++i) {
            const int k0 = kc * 32 + i * 8;
            const int plane = k0 >> 3;
            float4 u0 = *(const float4*)(xi + k0), u1 = *(const float4*)(xi + k0 + 4);
            float4 v0 = *(const float4*)(xj + k0), v1 = *(const float4*)(xj + k0 + 4);
            *(uint4*)(&Eb[(plane * 32 + row) * 16]) =
                pack8(u0.x*v0.x, u0.y*v0.y, u0.z*v0.z, u0.w*v0.w,
                      u1.x*v1.x, u1.y*v1.y, u1.z*v1.z, u1.w*v1.w);
        }
    }
    __syncthreads();    // drains stage 0,1 (vmcnt 0) + E writes

    f32x16 acc0 = (f32x16)(0.f), acc1 = (f32x16)(0.f);
    const int c0 = wid * 64 + lr;
    const int c1 = c0 + 32;

#pragma unroll 1
    for (int gks = 0; gks < 64; ++gks) {
        // issue stage for step gks+2 (3-deep pipeline)
        if (gks + 2 < 64) stageW(gks + 2);

        // MFMA for this step (K=16)
        {
            const int ks = gks & 31;
            bfrag a  = *(const bfrag*)(&Eb[((ks * 2 + kg) * 32 + lr) * 16]);
            const char* Wc = (const char*)Wb[gks % 3];
            bfrag w0 = *(const bfrag*)(Wc + (kg * 512 + c0) * 16);
            bfrag w1 = *(const bfrag*)(Wc + (kg * 512 + c1) * 16);
            acc0 = __builtin_amdgcn_mfma_f32_32x32x16_bf16(a, w0, acc0, 0, 0, 0);
            acc1 = __builtin_amdgcn_mfma_f32_32x32x16_bf16(a, w1, acc1, 0, 0, 0);
        }

        if (gks == 31) {
            // layer boundary: full sync (drains all stages), h1 in-place
            __syncthreads();
            float bv0 = b1[c0], bv1 = b1[c1];
#pragma unroll
            for (int reg = 0; reg < 16; ++reg) {
                int row = (reg & 3) + 8 * (reg >> 2) + 4 * kg;
                float v0h = fmaxf(acc0[reg] + bv0, 0.f);
                float v1h = fmaxf(acc1[reg] + bv1, 0.f);
                *(unsigned short*)(&Eb[((c0 >> 3) * 32 + row) * 16 + (c0 & 7) * 2]) =
                    (unsigned short)f2bf(v0h);
                *(unsigned short*)(&Eb[((c1 >> 3) * 32 + row) * 16 + (c1 & 7) * 2]) =
                    (unsigned short)f2bf(v1h);
            }
            acc0 = (f32x16)(0.f);
            acc1 = (f32x16)(0.f);
            __syncthreads();
        } else if (gks == 62) {
            // no stage issued this step: need last slice (63) complete
            asm volatile("s_waitcnt vmcnt(0) lgkmcnt(0)" ::: "memory");
            __builtin_amdgcn_s_barrier();
            __builtin_amdgcn_sched_barrier(0);
        } else if (gks < 63) {
            // steady state: 4 loads outstanding (stages gks+1, gks+2);
            // wait for the older pair -> vmcnt(2). lgkmcnt(0) orders the
            // buffer-reuse (read-before-overwrite across the barrier).
            asm volatile("s_waitcnt vmcnt(2) lgkmcnt(0)" ::: "memory");
            __builtin_amdgcn_s_barrier();
            __builtin_amdgcn_sched_barrier(0);
        }
    }

    // ---- fused layer-3: rowsum of relu(acc+b2)*w_out ----
    float rs[16];
    {
        float bv0 = b2[c0], bv1 = b2[c1];
        float wv0 = w_out[c0], wv1 = w_out[c1];
#pragma unroll
        for (int reg = 0; reg < 16; ++reg)
            rs[reg] = fmaxf(acc0[reg] + bv0, 0.f) * wv0
                    + fmaxf(acc1[reg] + bv1, 0.f) * wv1;
#pragma unroll
        for (int off = 1; off < 32; off <<= 1)
#pragma unroll
            for (int reg = 0; reg < 16; ++reg)
                rs[reg] += __shfl_xor(rs[reg], off);
    }
    __syncthreads();                       // all Wb reads done -> reuse as Pl
    float* Pl = (float*)&Wb[0][0];         // [8][32]
    if (lr == 0) {
#pragma unroll
        for (int reg = 0; reg < 16; ++reg) {
            int row = (reg & 3) + 8 * (reg >> 2) + 4 * kg;
            Pl[wid * 32 + row] = rs[reg];
        }
    }
    __syncthreads();
    if (tid < 32) {
        float v = b_out[0];
#pragma unroll
        for (int w = 0; w < 8; ++w) v += Pl[w * 32 + tid];
        int b = bc * 32 + tid;
        adj[b * (Nn * Nn) + pi * Nn + pj] = v;
        if (pi != pj) adj[b * (Nn * Nn) + pj * Nn + pi] = v;
    }
}

// ---------------------------------------------------------------------------
__global__ void softmax_az_kernel(const float* __restrict__ adj, float* __restrict__ a_z) {
    int b = blockIdx.x * 256 + threadIdx.x;
    if (b >= Bsz) return;
    const float* row = adj + b * (Nn * Nn) + Zi * Nn;
    float mx = row[0];
#pragma unroll
    for (int j = 1; j < Nn; ++j) mx = fmaxf(mx, row[j]);
    float e[Nn]; float s = 0.f;
#pragma unroll
    for (int j = 0; j < Nn; ++j) { e[j] = expf(row[j] - mx); s += e[j]; }
    float inv = 1.f / s;
#pragma unroll
    for (int j = 0; j < Nn; ++j) a_z[b * Nn + j] = e[j] * inv;
}

__global__ void mfix_kernel(const float* __restrict__ nf, const float* __restrict__ a_z,
                            float* __restrict__ m_fix) {
    int idx = blockIdx.x * 256 + threadIdx.x;
    int b = idx >> 9, f = idx & 511;
    float s = 0.f;
#pragma unroll
    for (int j = 0; j < Nn - 1; ++j)
        s += a_z[b * Nn + j] * nf[(b * Nn + j) * Ff + f];
    m_fix[idx] = s;
}

// ---------------------------------------------------------------------------
// gates: gi = (m_fix + az*col) @ Wih^T ; gh = col @ Whh^T (fp32 out)
// ---------------------------------------------------------------------------
__global__ __launch_bounds__(256, 3) void gates_kernel(
    const float* __restrict__ m_fix, const float* __restrict__ a_z,
    const float* __restrict__ colp,
    const unsigned short* __restrict__ Wihp, const unsigned short* __restrict__ Whhp,
    float* __restrict__ gi, float* __restrict__ gh)
{
    __shared__ __align__(16) char Wb[2][4 * 128 * 16];   // 2 x 8,192 B
    __shared__ __align__(16) char Ab[2][4 * 64 * 16];    // 2 x 4,096 B

    const int xb = blockIdx.x, bc = blockIdx.y, tid = threadIdx.x;
    const bool isGi = xb < 12;
    const int nb = isGi ? xb : xb - 12;
    const unsigned short* Wp = isGi ? Wihp : Whhp;
    float* C = isGi ? gi : gh;

    const int wid = tid >> 6;
    const int l   = tid & 63;
    const int bloc = tid >> 2;
    const int kc   = tid & 3;
    const int b    = bc * 64 + bloc;
    const float* cs = colp + b * Ff;
    const float* mf = m_fix + b * Ff;
    const float azv = isGi ? a_z[b * Nn + Zi] : 0.f;

    uint4 areg;
    auto loadA = [&](int k0) {
        const float* pc = cs + k0 + kc * 8;
        float4 c0 = *(const float4*)pc, c1 = *(const float4*)(pc + 4);
        if (isGi) {
            const float* pm = mf + k0 + kc * 8;
            float4 m0 = *(const float4*)pm, m1 = *(const float4*)(pm + 4);
            areg = pack8(m0.x + azv*c0.x, m0.y + azv*c0.y, m0.z + azv*c0.z, m0.w + azv*c0.w,
                         m1.x + azv*c1.x, m1.y + azv*c1.y, m1.z + azv*c1.z, m1.w + azv*c1.w);
        } else {
            areg = pack8(c0.x, c0.y, c0.z, c0.w, c1.x, c1.y, c1.z, c1.w);
        }
    };
    auto stageW = [&](int ks, int buf) {
        const int base = nb * 8192 + ks * 4 * 128;
#pragma unroll
        for (int i = 0; i < 2; ++i) {
            int cb = i * 256 + wid * 64;
            gl_lds16(Wp + (base + cb + l) * 8, (char*)Wb[buf] + cb * 16);
        }
    };

    stageW(0, 0);
    loadA(0);
    *(uint4*)(&Ab[0][(kc * 64 + bloc) * 16]) = areg;
    __syncthreads();

    const int lr = l & 31;
    const int kg = l >> 5;

    f32x16 acc[2];
    acc[0] = (f32x16)(0.f);
    acc[1] = (f32x16)(0.f);

#pragma unroll 1
    for (int ks = 0; ks < 16; ++ks) {
        const int cur = ks & 1;
        if (ks < 15) {
            stageW(ks + 1, cur ^ 1);
            loadA((ks + 1) * 32);
        }
#pragma unroll
        for (int s = 0; s < 2; ++s) {
            const int kcv = 2 * s + kg;
            bfrag a0 = *(const bfrag*)(&Ab[cur][(kcv * 64 + lr) * 16]);
            bfrag a1 = *(const bfrag*)(&Ab[cur][(kcv * 64 + 32 + lr) * 16]);
            bfrag bf = *(const bfrag*)(&Wb[cur][(kcv * 128 + wid * 32 + lr) * 16]);
            acc[0] = __builtin_amdgcn_mfma_f32_32x32x16_bf16(a0, bf, acc[0], 0, 0, 0);
            acc[1] = __builtin_amdgcn_mfma_f32_32x32x16_bf16(a1, bf, acc[1], 0, 0, 0);
        }
        if (ks < 15)
            *(uint4*)(&Ab[cur ^ 1][(kc * 64 + bloc) * 16]) = areg;
        __syncthreads();
    }

    const int colg = nb * 128 + wid * 32 + lr;
#pragma unroll
    for (int m = 0; m < 2; ++m) {
#pragma unroll
        for (int reg = 0; reg < 16; ++reg) {
            int row = m * 32 + (reg & 3) + 8 * (reg >> 2) + 4 * kg;
            C[(bc * 64 + row) * G3 + colg] = acc[m][reg];
        }
    }
}

// ---------------------------------------------------------------------------
__global__ void gru_kernel(const float* __restrict__ gi, const float* __restrict__ gh,
                           float* __restrict__ col) {
    int idx = blockIdx.x * 256 + threadIdx.x;   // 4 f per thread
    int b = idx >> 7, f = (idx & 127) * 4;
    const float* gib = gi + b * G3;
    const float* ghb = gh + b * G3;
    float4 ir = *(const float4*)(gib + f);
    float4 iz = *(const float4*)(gib + Ff + f);
    float4 in = *(const float4*)(gib + 2 * Ff + f);
    float4 hr = *(const float4*)(ghb + f);
    float4 hz = *(const float4*)(ghb + Ff + f);
    float4 hn = *(const float4*)(ghb + 2 * Ff + f);
    float4 h  = *(const float4*)(col + b * Ff + f);
    float4 o;
#define GRU1(c) { \
    float r = 1.f / (1.f + expf(-(ir.c + hr.c))); \
    float z = 1.f / (1.f + expf(-(iz.c + hz.c))); \
    float n = tanhf(in.c + r * hn.c); \
    o.c = (1.f - z) * n + z * h.c; }
    GRU1(x) GRU1(y) GRU1(z) GRU1(w)
#undef GRU1
    *(float4*)(col + b * Ff + f) = o;
}

// ---------------------------------------------------------------------------
extern "C" void kernel_launch(void* const* d_in, const int* in_sizes, int n_in,
                              void* d_out, int out_size, void* d_ws, size_t ws_size,
                              hipStream_t stream) {
    const float* nf    = (const float*)d_in[0];
    const float* W1    = (const float*)d_in[1];
    const float* b1    = (const float*)d_in[2];
    const float* W2    = (const float*)d_in[3];
    const float* b2    = (const float*)d_in[4];
    const float* w_out = (const float*)d_in[5];
    const float* b_out = (const float*)d_in[6];
    const float* W_ih  = (const float*)d_in[7];
    const float* W_hh  = (const float*)d_in[8];

    float* adj = (float*)d_out;                 // (B, 11, 11)
    float* col = adj + Bsz * Nn * Nn;           // (B, 512)

    unsigned short* W1p  = (unsigned short*)d_ws;        // packed, 512*512
    unsigned short* W2p  = W1p + Ff * Ff;
    unsigned short* Wihp = W2p + Ff * Ff;                // packed, 1536*512
    unsigned short* Whhp = Wihp + G3 * Ff;
    float* a_z   = (float*)(Whhp + G3 * Ff);
    float* m_fix = a_z + 16384;
    float* gi    = m_fix + Bsz * Ff;
    float* gh    = gi + Bsz * G3;

    init_col_kernel<<<(Bsz * Ff) / 256, 256, 0, stream>>>(nf, col);
    pack_w_kernel<<<(Ff * 64) / 256, 256, 0, stream>>>(W1, W1p, 9);
    pack_w_kernel<<<(Ff * 64) / 256, 256, 0, stream>>>(W2, W2p, 9);
    pack_w_kernel<<<(G3 * 64) / 256, 256, 0, stream>>>(W_ih, Wihp, 7);
    pack_w_kernel<<<(G3 * 64) / 256, 256, 0, stream>>>(W_hh, Whhp, 7);

    for (int t = 0; t < 3; ++t) {
        const int mode   = (t == 0) ? 0 : 1;
        const int npairs = (t == 0) ? 66 : 11;

        link_kernel<<<npairs * 32, 512, 0, stream>>>(nf, col, W1p, b1, W2p, b2,
                                                     w_out, b_out, adj, mode);
        softmax_az_kernel<<<Bsz / 256, 256, 0, stream>>>(adj, a_z);
        mfix_kernel<<<(Bsz * Ff) / 256, 256, 0, stream>>>(nf, a_z, m_fix);

        for (int s = 0; s < 3; ++s) {
            gates_kernel<<<dim3(24, 16), 256, 0, stream>>>(m_fix, a_z, col,
                                                           Wihp, Whhp, gi, gh);
            gru_kernel<<<(Bsz * Ff) / 4 / 256, 256, 0, stream>>>(gi, gh, col);
        }
    }
}